// Round 3
// baseline (354.706 us; speedup 1.0000x reference)
//
#include <hip/hip_runtime.h>

#define N_ROWS 4194304
#define RPT 4            // rows per thread, layer-blocked (R0 structure)
#define BLOCK 256

// ---- compile-time offsets (floats) into the packed weight buffer ----
// order: W_in b_in W_h1 b_h1 W_h2 b_h2 W_h3 b_h3 W_h4 b_h4 W_h5 b_h5
//        W_enc b_enc W_h6 b_h6 W_h7 b_h7 W_h8 b_h8 W_h9 b_h9 W_h10 b_h10
//        W_dec b_dec      (total 321 floats)
enum : int {
    O_W_in = 0,    O_b_in = 64,
    O_W_h1 = 72,   O_b_h1 = 104,
    O_W_h2 = 108,  O_b_h2 = 124,
    O_W_h3 = 128,  O_b_h3 = 144,
    O_W_h4 = 148,  O_b_h4 = 164,
    O_W_h5 = 168,  O_b_h5 = 184,
    O_W_enc = 188, O_b_enc = 192,
    O_W_h6 = 193,  O_b_h6 = 197,
    O_W_h7 = 201,  O_b_h7 = 217,
    O_W_h8 = 221,  O_b_h8 = 237,
    O_W_h9 = 241,  O_b_h9 = 257,
    O_W_h10 = 261, O_b_h10 = 277,
    O_W_dec = 281, O_b_dec = 313,
    W_TOTAL = 321
};

__device__ __forceinline__ float rrelu(float v) {
    // slope 0.0025 < 1  =>  leaky relu == max(v, slope*v)
    return fmaxf(v, 0.0025f * v);
}

// x = x + lin(rrelu(lin(x, Wa, ba)), Wb, bb)  (all 4x4), RPT rows blocked
__device__ __forceinline__ void resblock(float x[RPT][4],
                                         const float* __restrict__ Wa,
                                         const float* __restrict__ ba,
                                         const float* __restrict__ Wb,
                                         const float* __restrict__ bb) {
    float t[RPT][4];
#pragma unroll
    for (int j = 0; j < 4; ++j) {
#pragma unroll
        for (int k = 0; k < RPT; ++k) {
            float acc = ba[j];
#pragma unroll
            for (int i = 0; i < 4; ++i) acc = fmaf(x[k][i], Wa[i * 4 + j], acc);
            t[k][j] = rrelu(acc);
        }
    }
#pragma unroll
    for (int j = 0; j < 4; ++j) {
#pragma unroll
        for (int k = 0; k < RPT; ++k) {
            float acc = bb[j];
#pragma unroll
            for (int i = 0; i < 4; ++i) acc = fmaf(t[k][i], Wb[i * 4 + j], acc);
            x[k][j] += acc;
        }
    }
}

__global__ __launch_bounds__(BLOCK) void ann_fused_kernel(
    const float* __restrict__ x_in, const float* __restrict__ wf,
    float* __restrict__ out) {
    const int tid = blockIdx.x * BLOCK + threadIdx.x;
    const int T = N_ROWS / RPT;  // rows handled: tid + k*T (coalesced per instr)

    // ---- inputs: 2x float4 per row ----
    float xin[RPT][8];
#pragma unroll
    for (int k = 0; k < RPT; ++k) {
        const float4* p =
            reinterpret_cast<const float4*>(x_in + (size_t)(tid + k * T) * 8);
        float4 a = p[0], b = p[1];
        xin[k][0] = a.x; xin[k][1] = a.y; xin[k][2] = a.z; xin[k][3] = a.w;
        xin[k][4] = b.x; xin[k][5] = b.y; xin[k][6] = b.z; xin[k][7] = b.w;
    }

    // ---- layer "in": 8->8, rrelu.  All weight reads: wf[const] -> s_load ----
    float t8[RPT][8];
#pragma unroll
    for (int j = 0; j < 8; ++j) {
#pragma unroll
        for (int k = 0; k < RPT; ++k) {
            float acc = wf[O_b_in + j];
#pragma unroll
            for (int i = 0; i < 8; ++i)
                acc = fmaf(xin[k][i], wf[O_W_in + i * 8 + j], acc);
            t8[k][j] = rrelu(acc);
        }
    }

    // ---- h1: 8->4, NO activation ----
    float x[RPT][4];
#pragma unroll
    for (int j = 0; j < 4; ++j) {
#pragma unroll
        for (int k = 0; k < RPT; ++k) {
            float acc = wf[O_b_h1 + j];
#pragma unroll
            for (int i = 0; i < 8; ++i)
                acc = fmaf(t8[k][i], wf[O_W_h1 + i * 4 + j], acc);
            x[k][j] = acc;
        }
    }

    resblock(x, wf + O_W_h2, wf + O_b_h2, wf + O_W_h3, wf + O_b_h3);
    resblock(x, wf + O_W_h4, wf + O_b_h4, wf + O_W_h5, wf + O_b_h5);

    // ---- encode: 4->1, rrelu ----
    float e[RPT];
#pragma unroll
    for (int k = 0; k < RPT; ++k) {
        float acc = wf[O_b_enc];
#pragma unroll
        for (int i = 0; i < 4; ++i) acc = fmaf(x[k][i], wf[O_W_enc + i], acc);
        e[k] = rrelu(acc);
    }

    // ---- h6: 1->4, rrelu ----
#pragma unroll
    for (int j = 0; j < 4; ++j) {
#pragma unroll
        for (int k = 0; k < RPT; ++k) {
            x[k][j] = rrelu(fmaf(e[k], wf[O_W_h6 + j], wf[O_b_h6 + j]));
        }
    }

    resblock(x, wf + O_W_h7, wf + O_b_h7, wf + O_W_h8, wf + O_b_h8);
    resblock(x, wf + O_W_h9, wf + O_b_h9, wf + O_W_h10, wf + O_b_h10);

    // ---- decode: 4->8, rrelu ----
    float d[RPT][8];
#pragma unroll
    for (int j = 0; j < 8; ++j) {
#pragma unroll
        for (int k = 0; k < RPT; ++k) {
            float acc = wf[O_b_dec + j];
#pragma unroll
            for (int i = 0; i < 4; ++i)
                acc = fmaf(x[k][i], wf[O_W_dec + i * 8 + j], acc);
            d[k][j] = rrelu(acc);
        }
    }

    // ---- stores ----
#pragma unroll
    for (int k = 0; k < RPT; ++k) {
        const int row = tid + k * T;
        out[row] = e[k];  // encode stream: 1 dword/lane, coalesced
        float4* q = reinterpret_cast<float4*>(out + N_ROWS + (size_t)row * 8);
        q[0] = make_float4(d[k][0], d[k][1], d[k][2], d[k][3]);
        q[1] = make_float4(d[k][4], d[k][5], d[k][6], d[k][7]);
    }
}

extern "C" void kernel_launch(void* const* d_in, const int* in_sizes, int n_in,
                              void* d_out, int out_size, void* d_ws, size_t ws_size,
                              hipStream_t stream) {
    const float* x_in = (const float*)d_in[0];
    float* wf = (float*)d_ws;  // packed weights live in workspace

    // Pack the 26 weight/bias arrays contiguously (D2D async copies on stream:
    // graph-capture safe). Sizes fixed by the model definition.
    static const int sz[26] = {64, 8, 32, 4, 16, 4, 16, 4, 16, 4, 16, 4,
                               4,  1, 4,  4, 16, 4, 16, 4, 16, 4, 16, 4, 32, 8};
    int off = 0;
    for (int i = 0; i < 26; ++i) {
        hipMemcpyAsync(wf + off, d_in[1 + i], sz[i] * sizeof(float),
                       hipMemcpyDeviceToDevice, stream);
        off += sz[i];
    }

    float* out = (float*)d_out;
    const int total_threads = N_ROWS / RPT;
    dim3 grid(total_threads / BLOCK), block(BLOCK);
    ann_fused_kernel<<<grid, block, 0, stream>>>(x_in, wf, out);
}

// Round 4
// 316.522 us; speedup vs baseline: 1.1206x; 1.1206x over previous
//
#include <hip/hip_runtime.h>

#define N_ROWS 4194304
#define RPT 4
#define BLOCK 256

// ---- packed weight buffer offsets (floats); every array 16B-aligned ----
enum : int {
    O_W_in = 0,    O_b_in = 64,
    O_W_h1 = 72,   O_b_h1 = 104,
    O_W_h2 = 108,  O_b_h2 = 124,
    O_W_h3 = 128,  O_b_h3 = 144,
    O_W_h4 = 148,  O_b_h4 = 164,
    O_W_h5 = 168,  O_b_h5 = 184,
    O_W_enc = 188, O_b_enc = 192,  // b_enc padded 1->4
    O_W_h6 = 196,  O_b_h6 = 200,
    O_W_h7 = 204,  O_b_h7 = 220,
    O_W_h8 = 224,  O_b_h8 = 240,
    O_W_h9 = 244,  O_b_h9 = 260,
    O_W_h10 = 264, O_b_h10 = 280,
    O_W_dec = 284, O_b_dec = 316,
    W_TOTAL = 324
};

__device__ __forceinline__ float rrelu(float v) {
    return fmaxf(v, 0.0025f * v);  // slope 0.0025 < 1
}

// y = [rrelu](x @ W + b), column-group blocked: every W access is a
// contiguous aligned float4 held in a register across 4*RPT FMAs.
template <int FI, int FO, bool RELU>
__device__ __forceinline__ void lin(const float* __restrict__ wf, int Woff,
                                    int boff, const float (&x)[RPT][FI],
                                    float (&y)[RPT][FO]) {
#pragma unroll
    for (int jg = 0; jg < FO; jg += 4) {
        float4 b4 = *reinterpret_cast<const float4*>(wf + boff + jg);
        float acc[RPT][4];
#pragma unroll
        for (int k = 0; k < RPT; ++k) {
            acc[k][0] = b4.x; acc[k][1] = b4.y;
            acc[k][2] = b4.z; acc[k][3] = b4.w;
        }
#pragma unroll
        for (int i = 0; i < FI; ++i) {
            float4 w4 = *reinterpret_cast<const float4*>(wf + Woff + i * FO + jg);
            float wa[4] = {w4.x, w4.y, w4.z, w4.w};
#pragma unroll
            for (int k = 0; k < RPT; ++k)
#pragma unroll
                for (int c = 0; c < 4; ++c)
                    acc[k][c] = fmaf(x[k][i], wa[c], acc[k][c]);
        }
#pragma unroll
        for (int k = 0; k < RPT; ++k)
#pragma unroll
            for (int c = 0; c < 4; ++c)
                y[k][jg + c] = RELU ? rrelu(acc[k][c]) : acc[k][c];
    }
}

// y += x @ W + b   (residual second half)
template <int FI, int FO>
__device__ __forceinline__ void lin_add(const float* __restrict__ wf, int Woff,
                                        int boff, const float (&x)[RPT][FI],
                                        float (&y)[RPT][FO]) {
#pragma unroll
    for (int jg = 0; jg < FO; jg += 4) {
        float4 b4 = *reinterpret_cast<const float4*>(wf + boff + jg);
        float acc[RPT][4];
#pragma unroll
        for (int k = 0; k < RPT; ++k) {
            acc[k][0] = b4.x; acc[k][1] = b4.y;
            acc[k][2] = b4.z; acc[k][3] = b4.w;
        }
#pragma unroll
        for (int i = 0; i < FI; ++i) {
            float4 w4 = *reinterpret_cast<const float4*>(wf + Woff + i * FO + jg);
            float wa[4] = {w4.x, w4.y, w4.z, w4.w};
#pragma unroll
            for (int k = 0; k < RPT; ++k)
#pragma unroll
                for (int c = 0; c < 4; ++c)
                    acc[k][c] = fmaf(x[k][i], wa[c], acc[k][c]);
        }
#pragma unroll
        for (int k = 0; k < RPT; ++k)
#pragma unroll
            for (int c = 0; c < 4; ++c) y[k][jg + c] += acc[k][c];
    }
}

__device__ __forceinline__ void resblock(const float* __restrict__ wf, int Oa,
                                         int Oba, int Ob, int Obb,
                                         float (&x)[RPT][4]) {
    float t[RPT][4];
    lin<4, 4, true>(wf, Oa, Oba, x, t);
    lin_add<4, 4>(wf, Ob, Obb, t, x);
}

__global__ __launch_bounds__(BLOCK) void ann_fused_kernel(
    const float* __restrict__ x_in, const float* __restrict__ wf,
    float* __restrict__ out) {
    const int tid = blockIdx.x * BLOCK + threadIdx.x;
    const int T = N_ROWS / RPT;  // rows: tid + k*T, coalesced per instruction

    float xin[RPT][8];
#pragma unroll
    for (int k = 0; k < RPT; ++k) {
        const float4* p =
            reinterpret_cast<const float4*>(x_in + (size_t)(tid + k * T) * 8);
        float4 a = p[0], b = p[1];
        xin[k][0] = a.x; xin[k][1] = a.y; xin[k][2] = a.z; xin[k][3] = a.w;
        xin[k][4] = b.x; xin[k][5] = b.y; xin[k][6] = b.z; xin[k][7] = b.w;
    }

    float t8[RPT][8];
    lin<8, 8, true>(wf, O_W_in, O_b_in, xin, t8);
    float x[RPT][4];
    lin<8, 4, false>(wf, O_W_h1, O_b_h1, t8, x);

    resblock(wf, O_W_h2, O_b_h2, O_W_h3, O_b_h3, x);
    resblock(wf, O_W_h4, O_b_h4, O_W_h5, O_b_h5, x);

    // encode: 4->1, rrelu
    float4 we = *reinterpret_cast<const float4*>(wf + O_W_enc);
    float be = wf[O_b_enc];
    float e[RPT];
#pragma unroll
    for (int k = 0; k < RPT; ++k) {
        float a = fmaf(x[k][0], we.x, be);
        a = fmaf(x[k][1], we.y, a);
        a = fmaf(x[k][2], we.z, a);
        a = fmaf(x[k][3], we.w, a);
        e[k] = rrelu(a);
    }

    // h6: 1->4, rrelu
    float4 w6 = *reinterpret_cast<const float4*>(wf + O_W_h6);
    float4 b6 = *reinterpret_cast<const float4*>(wf + O_b_h6);
#pragma unroll
    for (int k = 0; k < RPT; ++k) {
        x[k][0] = rrelu(fmaf(e[k], w6.x, b6.x));
        x[k][1] = rrelu(fmaf(e[k], w6.y, b6.y));
        x[k][2] = rrelu(fmaf(e[k], w6.z, b6.z));
        x[k][3] = rrelu(fmaf(e[k], w6.w, b6.w));
    }

    resblock(wf, O_W_h7, O_b_h7, O_W_h8, O_b_h8, x);
    resblock(wf, O_W_h9, O_b_h9, O_W_h10, O_b_h10, x);

    float d[RPT][8];
    lin<4, 8, true>(wf, O_W_dec, O_b_dec, x, d);

#pragma unroll
    for (int k = 0; k < RPT; ++k) {
        const int row = tid + k * T;
        out[row] = e[k];  // encode stream
        float4* q = reinterpret_cast<float4*>(out + N_ROWS + (size_t)row * 8);
        q[0] = make_float4(d[k][0], d[k][1], d[k][2], d[k][3]);
        q[1] = make_float4(d[k][4], d[k][5], d[k][6], d[k][7]);
    }
}

// ---- single-dispatch weight packing (replaces 26 memcpy graph nodes) ----
struct SrcPtrs { const float* p[26]; };

__global__ void pack_weights(SrcPtrs s, float* __restrict__ wf) {
    const int t = threadIdx.x;  // one block of 64
    const int off[26] = {O_W_in,  O_b_in,  O_W_h1,  O_b_h1,  O_W_h2, O_b_h2,
                         O_W_h3,  O_b_h3,  O_W_h4,  O_b_h4,  O_W_h5, O_b_h5,
                         O_W_enc, O_b_enc, O_W_h6,  O_b_h6,  O_W_h7, O_b_h7,
                         O_W_h8,  O_b_h8,  O_W_h9,  O_b_h9,  O_W_h10,
                         O_b_h10, O_W_dec, O_b_dec};
    const int sz[26] = {64, 8, 32, 4, 16, 4, 16, 4, 16, 4, 16, 4, 4,
                        1,  4, 4,  16, 4, 16, 4, 16, 4, 16, 4, 32, 8};
#pragma unroll 1
    for (int g = 0; g < 26; ++g)
        if (t < sz[g]) wf[off[g] + t] = s.p[g][t];
}

extern "C" void kernel_launch(void* const* d_in, const int* in_sizes, int n_in,
                              void* d_out, int out_size, void* d_ws, size_t ws_size,
                              hipStream_t stream) {
    const float* x_in = (const float*)d_in[0];
    float* wf = (float*)d_ws;

    SrcPtrs s;
    for (int i = 0; i < 26; ++i) s.p[i] = (const float*)d_in[1 + i];
    pack_weights<<<1, 64, 0, stream>>>(s, wf);

    float* out = (float*)d_out;
    const int total_threads = N_ROWS / RPT;
    dim3 grid(total_threads / BLOCK), block(BLOCK);
    ann_fused_kernel<<<grid, block, 0, stream>>>(x_in, wf, out);
}